// Round 10
// baseline (10066.088 us; speedup 1.0000x reference)
//
#include <hip/hip_runtime.h>
#include <math.h>

// ---------------------------------------------------------------------------
// Persistent 2-layer LSTM via MFMA split-bf16 (hi+lo, 3-term) fp32 emulation.
// 208 blocks x 512 thr (1/CU). Pipeline: A(64)=layer0 s=t | B(128)=layer1
// s=t-1 | C(16)=proj s=t-2.
// R13: persistent-register weights (zero in-loop weight loads; FETCH -25x).
// R16: L2-CACHED h staging. Diagnosis: all rounds pinned at ~5-6 TB/s of
// sc0/sc1 LLC-bypass staging traffic (43 MB/step; every B block re-reads all
// of h0+h1). Stage loads are now PLAIN (L1/L2-cacheable) so blocks sharing an
// XCD share one LLC fetch; correctness vs 2-step-stale L2 lines restored by a
// per-step agent-scope acquire fence (buffer_inv sc1) in the flag barrier.
// h stores remain sc0/sc1 write-through (LLC-visible before flag store).
// Staging schedule, waits, and root barrier are R13 verbatim.
// ---------------------------------------------------------------------------

typedef __attribute__((ext_vector_type(8))) short short8;
typedef __attribute__((ext_vector_type(4))) float f32x4;

constexpr int kV = 256, kH = 1024, kB = 32, kS = 512, G4H = 4096;
constexpr int NT = 512, NBLK = 208;
constexpr int NA = 64, B0 = 64, C0 = 192, ROOT = NBLK - 1;

// ws layout in SHORT units
constexpr long SZW = 4194304L;            // shorts per packed 1024x4096 matrix
constexpr long SZY = 262144L;             // shorts per packed Why array
constexpr long WP0H = 0,        WP0L = SZW;
constexpr long WP1XH = 2*SZW,   WP1XL = 3*SZW;
constexpr long WP1HH = 4*SZW,   WP1HL = 5*SZW;
constexpr long WYH  = 6*SZW,    WYL  = 6*SZW + SZY;
constexpr long HOFF = 6*SZW + 2*SZY;      // h arrays: h0h[2][32K],h0l,h1h,h1l

#define MFMA(a,b,c) __builtin_amdgcn_mfma_f32_16x16x32_bf16(a, b, c, 0, 0, 0)

#define VM_WAIT(n) do { \
    asm volatile("s_waitcnt vmcnt(" #n ")" ::: "memory"); \
    __builtin_amdgcn_sched_barrier(0); \
  } while (0)

// asm weight load (prevents compiler rematerialization from memory)
#define WLOAD(dst, p) \
  asm volatile("global_load_dwordx4 %0, %1, off" : "=v"(dst) : "v"(p) : "memory")

__device__ __forceinline__ float sigmoidf_(float v) { return 1.f / (1.f + expf(-v)); }

__device__ __forceinline__ void bf16split(float w, unsigned& hi, unsigned& lo) {
  unsigned u = __float_as_uint(w);
  unsigned r = (u + 0x7fffu + ((u >> 16) & 1u)) >> 16;
  float res = w - __uint_as_float(r << 16);
  unsigned u2 = __float_as_uint(res);
  unsigned r2 = (u2 + 0x7fffu + ((u2 >> 16) & 1u)) >> 16;
  hi = r; lo = r2;
}

// ---------------- coherent (cache-bypass) helpers --------------------------

__device__ __forceinline__ void coh_store_u32(unsigned* p, unsigned v) {
  asm volatile("global_store_dword %0, %1, off sc0 sc1" :: "v"(p), "v"(v) : "memory");
}
__device__ __forceinline__ void coh_store_u16(unsigned short* p, unsigned v) {
  asm volatile("global_store_short %0, %1, off sc0 sc1" :: "v"(p), "v"(v) : "memory");
}
__device__ __forceinline__ unsigned coh_load_u32(const unsigned* p) {
  unsigned v;
  asm volatile("global_load_dword %0, %1, off sc0 sc1\n\ts_waitcnt vmcnt(0)"
               : "=v"(v) : "v"(p) : "memory");
  return v;
}

// issue one 256-k quarter of h (hi+lo): 4 PLAIN cacheable 16B loads, NO wait.
// (L2-shared across the XCD; staleness handled by per-step acquire fence.)
__device__ __forceinline__ void stage_issue4(const unsigned short* pr0h,
                                             const unsigned short* pr1h,
                                             const unsigned short* pr0l,
                                             const unsigned short* pr1l,
                                             int qoff,   // qtr*256 (shorts)
                                             float4& a, float4& b,
                                             float4& c, float4& d) {
  asm volatile(
      "global_load_dwordx4 %0, %4, off\n\t"
      "global_load_dwordx4 %1, %5, off\n\t"
      "global_load_dwordx4 %2, %6, off\n\t"
      "global_load_dwordx4 %3, %7, off"
      : "=&v"(a), "=&v"(b), "=&v"(c), "=&v"(d)
      : "v"(pr0h + qoff), "v"(pr1h + qoff), "v"(pr0l + qoff), "v"(pr1l + qoff)
      : "memory");
}

__device__ __forceinline__ void stage_write4(short8* HH, short8* HL,
                                             int b0_, int kg,
                                             const float4& a, const float4& b,
                                             const float4& c, const float4& d) {
  HH[b0_ * 33 + kg]        = __builtin_bit_cast(short8, a);
  HH[(b0_ + 16) * 33 + kg] = __builtin_bit_cast(short8, b);
  HL[b0_ * 33 + kg]        = __builtin_bit_cast(short8, c);
  HL[(b0_ + 16) * 33 + kg] = __builtin_bit_cast(short8, d);
}

// barrier that does NOT drain vmcnt: LDS-drain + raw s_barrier.
__device__ __forceinline__ void lds_barrier() {
  asm volatile("s_waitcnt lgkmcnt(0)" ::: "memory");
  __builtin_amdgcn_sched_barrier(0);
  __builtin_amdgcn_s_barrier();
  __builtin_amdgcn_sched_barrier(0);
}

// ---------------- two-hop root flag barrier + per-step acquire -------------

__device__ __forceinline__ void flag_barrier(unsigned* arrive, unsigned* gen,
                                             int blk, int tid, int t) {
  __syncthreads();                         // drains vmcnt per wave
  const unsigned target = (unsigned)(t + 1);
  if (tid == 0) coh_store_u32(arrive + blk * 16, target);
  if (blk == ROOT) {
    if (tid < 64) {
      const unsigned* q0 = arrive + tid * 16;
      const unsigned* q1 = arrive + (64 + tid) * 16;
      const unsigned* q2 = arrive + (128 + tid) * 16;
      const int i3 = (192 + tid < NBLK) ? (192 + tid) : 0;
      const unsigned* q3 = arrive + i3 * 16;
      int guard = 0;
      for (;;) {
        unsigned a, b, c, d;
        asm volatile(
            "global_load_dword %0, %4, off sc0 sc1\n\t"
            "global_load_dword %1, %5, off sc0 sc1\n\t"
            "global_load_dword %2, %6, off sc0 sc1\n\t"
            "global_load_dword %3, %7, off sc0 sc1\n\t"
            "s_waitcnt vmcnt(0)"
            : "=&v"(a), "=&v"(b), "=&v"(c), "=&v"(d)
            : "v"(q0), "v"(q1), "v"(q2), "v"(q3) : "memory");
        bool ok = (a >= target) && (b >= target) && (c >= target) && (d >= target);
        if (__all(ok)) break;
        if (++guard > (1 << 17)) break;    // anti-hang valve
      }
      if (tid == 0) coh_store_u32(gen, target);
    }
  } else {
    if (tid == 0) {
      int guard = 0;
      while (coh_load_u32(gen) < target) {
        __builtin_amdgcn_s_sleep(1);
        if (++guard > (1 << 17)) break;    // anti-hang valve
      }
    }
  }
  __syncthreads();
  // agent-scope acquire: invalidate L1+L2 so next step's PLAIN h loads
  // cannot hit lines staled by other-XCD writes (parity reuse period = 2).
  __builtin_amdgcn_fence(__ATOMIC_ACQUIRE, "agent");
  __builtin_amdgcn_sched_barrier(0);
}

// -------------------------- prep kernels -----------------------------------

__global__ void pack_w(const float* __restrict__ in, unsigned short* __restrict__ hi,
                       unsigned short* __restrict__ lo, int ncols) {
  int id = blockIdx.x * 256 + threadIdx.x;
  int slab = id / ncols, row = id % ncols;   // slab < 128
  int k0 = (slab >> 2) * 32 + (slab & 3) * 8;
  long ob = ((long)slab * ncols + row) * 8;
  #pragma unroll
  for (int e = 0; e < 8; ++e) {
    float w = in[(long)(k0 + e) * ncols + row];
    unsigned h_, l_;
    bf16split(w, h_, l_);
    hi[ob + e] = (unsigned short)h_;
    lo[ob + e] = (unsigned short)l_;
  }
}

__global__ void zero_state(unsigned* __restrict__ p, int n) {
  int i = blockIdx.x * 256 + threadIdx.x;
  if (i < n) coh_store_u32(p + i, 0u);   // write-through: LLC-visible zeros
}

// -------------------------- main persistent kernel -------------------------

extern "C" __global__ void __launch_bounds__(512, 1)
lstm_persist(const int* __restrict__ x,
             const float* __restrict__ Wx0,
             const float* __restrict__ b0v,
             const float* __restrict__ b1v,
             const float* __restrict__ byv,
             unsigned short* __restrict__ wss,
             float* __restrict__ out) {
  const short8* wp0h  = (const short8*)(wss + WP0H);
  const short8* wp0l  = (const short8*)(wss + WP0L);
  const short8* wp1xh = (const short8*)(wss + WP1XH);
  const short8* wp1xl = (const short8*)(wss + WP1XL);
  const short8* wp1hh = (const short8*)(wss + WP1HH);
  const short8* wp1hl = (const short8*)(wss + WP1HL);
  const short8* wyh   = (const short8*)(wss + WYH);
  const short8* wyl   = (const short8*)(wss + WYL);
  unsigned short* h0h = wss + HOFF;            // [2][32][1024]
  unsigned short* h0l = h0h + 65536;
  unsigned short* h1h = h0h + 131072;
  unsigned short* h1l = h0h + 196608;
  unsigned* arrive = (unsigned*)(h0h + 262144);  // stride-16 flags
  unsigned* gen = arrive + 4096;

  const int tid = threadIdx.x, blk = blockIdx.x;
  const int lane = tid & 63, m = lane & 15, quad = lane >> 4, w = tid >> 6;
  const int b0_ = tid >> 5, kg = tid & 31;     // staging row / chunk
  const int kg8 = kg * 8;

  __shared__ short8 HSH[2][32 * 33];   // 2 x 16.5 KB  h hi quarter (dbuf)
  __shared__ short8 HSL[2][32 * 33];   // 2 x 16.5 KB  h lo quarter (dbuf)
  __shared__ float gx[4096];           // 16 KB partial-sum exchange

  if (blk < NA) {
    // ================= A: layer0 cell, s = t ===========================
    const int g = w >> 1, kh = w & 1, j0A = blk * 16;
    const int ue = tid >> 5, be = tid & 31, j2e = j0A + ue;
    const float bA0 = b0v[j2e],          bA1 = b0v[kH + j2e];
    const float bA2 = b0v[2 * kH + j2e], bA3 = b0v[3 * kH + j2e];
    // persistent weight slice: 16 kk (parity kh) x hi/lo = 128 VGPR
    const short8* ah_ = wp0h + quad * 4096 + (g * 1024 + j0A + m);
    const short8* al_ = wp0l + quad * 4096 + (g * 1024 + j0A + m);
    short8 wah[16], wal[16];
    #pragma unroll
    for (int i = 0; i < 16; ++i) {
      WLOAD(wah[i], &ah_[(2 * i + kh) * 16384]);
      WLOAD(wal[i], &al_[(2 * i + kh) * 16384]);
    }
    VM_WAIT(0);
    float c0r = 0.f;

    #pragma unroll 1
    for (int t = 0; t < kS + 2; ++t) {
      const int s = t;
      if (s < kS) {
        const int rpar = (s + 1) & 1;
        const unsigned short* gH = h0h + rpar * 32768;
        const unsigned short* gL = h0l + rpar * 32768;
        const unsigned short* pH0 = gH + b0_ * 1024 + kg8;
        const unsigned short* pH1 = pH0 + 16 * 1024;
        const unsigned short* pL0 = gL + b0_ * 1024 + kg8;
        const unsigned short* pL1 = pL0 + 16 * 1024;
        // xs first (compiler load + its own drain), then asm gather, stages
        const int xs = x[be * kS + s];
        const float* wxp = Wx0 + (long)xs * G4H + j2e;
        float wxi, wxf, wxg, wxo;
        asm volatile(
            "global_load_dword %0, %4, off\n\t"
            "global_load_dword %1, %5, off\n\t"
            "global_load_dword %2, %6, off\n\t"
            "global_load_dword %3, %7, off"
            : "=&v"(wxi), "=&v"(wxf), "=&v"(wxg), "=&v"(wxo)
            : "v"(wxp), "v"(wxp + kH), "v"(wxp + 2 * kH), "v"(wxp + 3 * kH)
            : "memory");
        float4 st[2][4];
        stage_issue4(pH0, pH1, pL0, pL1, 0, st[0][0], st[0][1], st[0][2], st[0][3]);
        f32x4 acc0 = {0.f, 0.f, 0.f, 0.f}, acc1 = {0.f, 0.f, 0.f, 0.f};
        #pragma unroll
        for (int ph = 0; ph < 4; ++ph) {
          if (ph < 3)
            stage_issue4(pH0, pH1, pL0, pL1, (ph + 1) * 256,
                         st[(ph + 1) & 1][0], st[(ph + 1) & 1][1],
                         st[(ph + 1) & 1][2], st[(ph + 1) & 1][3]);
          if (ph < 3) { VM_WAIT(4); } else { VM_WAIT(0); }
          stage_write4(&HSH[ph & 1][0], &HSL[ph & 1][0], b0_, kg,
                       st[ph & 1][0], st[ph & 1][1], st[ph & 1][2], st[ph & 1][3]);
          lds_barrier();
          #pragma unroll
          for (int i2 = 0; i2 < 4; ++i2) {
            const int kl = 2 * i2 + kh;          // runtime kh, fine
            const int widx = ph * 4 + i2;        // compile-time
            short8 bh0 = HSH[ph & 1][m * 33 + kl * 4 + quad];
            short8 bl0 = HSL[ph & 1][m * 33 + kl * 4 + quad];
            short8 bh1 = HSH[ph & 1][(16 + m) * 33 + kl * 4 + quad];
            short8 bl1 = HSL[ph & 1][(16 + m) * 33 + kl * 4 + quad];
            acc0 = MFMA(wah[widx], bh0, acc0);
            acc0 = MFMA(wah[widx], bl0, acc0);
            acc0 = MFMA(wal[widx], bh0, acc0);
            acc1 = MFMA(wah[widx], bh1, acc1);
            acc1 = MFMA(wah[widx], bl1, acc1);
            acc1 = MFMA(wal[widx], bh1, acc1);
          }
        }
        #pragma unroll
        for (int r = 0; r < 4; ++r) {
          gx[(kh * 64 + g * 16 + quad * 4 + r) * 32 + m]      = acc0[r];
          gx[(kh * 64 + g * 16 + quad * 4 + r) * 32 + 16 + m] = acc1[r];
        }
        lds_barrier();
        {
          float gi = gx[(0 + ue) * 32 + be]  + gx[(64 + 0 + ue) * 32 + be]  + wxi + bA0;
          float gf = gx[(16 + ue) * 32 + be] + gx[(64 + 16 + ue) * 32 + be] + wxf + bA1;
          float gg = gx[(32 + ue) * 32 + be] + gx[(64 + 32 + ue) * 32 + be] + wxg + bA2;
          float go = gx[(48 + ue) * 32 + be] + gx[(64 + 48 + ue) * 32 + be] + wxo + bA3;
          float cc = sigmoidf_(gf) * c0r + sigmoidf_(gi) * tanhf(gg);
          float hh = sigmoidf_(go) * tanhf(cc);
          c0r = cc;
          unsigned h_, l_;
          bf16split(hh, h_, l_);
          const int wpar = s & 1;
          coh_store_u16(h0h + wpar * 32768 + be * 1024 + j2e, h_);
          coh_store_u16(h0l + wpar * 32768 + be * 1024 + j2e, l_);
        }
      }
      if (t < kS + 1) flag_barrier(arrive, gen, blk, tid, t);
    }
  } else if (blk < C0) {
    // ================= B: layer1 cell, s = t-1 =========================
    const int hf = w >> 2, mt = (w >> 1) & 1, kq = w & 1;
    const int rowB = mt * 16 + m;
    const int growB = (rowB >> 3) * 1024 + (blk - B0) * 8 + (rowB & 7);
    const int ub = tid >> 5;
    const int j2b = (blk - B0) * 8 + (ub & 7);
    const float bB0 = b1v[j2b],          bB1 = b1v[kH + j2b];
    const float bB2 = b1v[2 * kH + j2b], bB3 = b1v[3 * kH + j2b];
    // persistent slice: matrix hf, 16 kk (parity kq) x hi/lo = 128 VGPR
    const short8* bh_ = (hf ? wp1hh : wp1xh) + quad * 4096 + growB;
    const short8* bl_ = (hf ? wp1hl : wp1xl) + quad * 4096 + growB;
    short8 wbh[16], wbl[16];
    #pragma unroll
    for (int i = 0; i < 16; ++i) {
      WLOAD(wbh[i], &bh_[(2 * i + kq) * 16384]);
      WLOAD(wbl[i], &bl_[(2 * i + kq) * 16384]);
    }
    VM_WAIT(0);
    float c1r = 0.f;

    #pragma unroll 1
    for (int t = 0; t < kS + 2; ++t) {
      const int s = t - 1;
      if (s >= 0 && s < kS) {
        const unsigned short* g0h = h0h + (s & 1) * 32768;
        const unsigned short* g0l = h0l + (s & 1) * 32768;
        const unsigned short* g1h = h1h + ((s + 1) & 1) * 32768;
        const unsigned short* g1l = h1l + ((s + 1) & 1) * 32768;
        const unsigned short* pA0h = g0h + b0_ * 1024 + kg8;
        const unsigned short* pA1h = pA0h + 16 * 1024;
        const unsigned short* pA0l = g0l + b0_ * 1024 + kg8;
        const unsigned short* pA1l = pA0l + 16 * 1024;
        const unsigned short* pB0h = g1h + b0_ * 1024 + kg8;
        const unsigned short* pB1h = pB0h + 16 * 1024;
        const unsigned short* pB0l = g1l + b0_ * 1024 + kg8;
        const unsigned short* pB1l = pB0l + 16 * 1024;
        float4 st[2][4];
        stage_issue4(pA0h, pA1h, pA0l, pA1l, 0,
                     st[0][0], st[0][1], st[0][2], st[0][3]);
        f32x4 acc0 = {0.f, 0.f, 0.f, 0.f}, acc1 = {0.f, 0.f, 0.f, 0.f};
        #pragma unroll
        for (int ph = 0; ph < 8; ++ph) {
          const int half = ph >> 2, qtr = ph & 3;
          if (ph < 7) {
            const int p1 = ph + 1, q1 = p1 & 3;
            if ((p1 >> 2) == 0)
              stage_issue4(pA0h, pA1h, pA0l, pA1l, q1 * 256,
                           st[p1 & 1][0], st[p1 & 1][1], st[p1 & 1][2], st[p1 & 1][3]);
            else
              stage_issue4(pB0h, pB1h, pB0l, pB1l, q1 * 256,
                           st[p1 & 1][0], st[p1 & 1][1], st[p1 & 1][2], st[p1 & 1][3]);
          }
          if (ph < 7) { VM_WAIT(4); } else { VM_WAIT(0); }
          stage_write4(&HSH[ph & 1][0], &HSL[ph & 1][0], b0_, kg,
                       st[ph & 1][0], st[ph & 1][1], st[ph & 1][2], st[ph & 1][3]);
          lds_barrier();
          if (hf == half) {
            #pragma unroll
            for (int i2 = 0; i2 < 4; ++i2) {
              const int kl = 2 * i2 + kq;
              const int widx = qtr * 4 + i2;
              short8 bh0 = HSH[ph & 1][m * 33 + kl * 4 + quad];
              short8 bl0 = HSL[ph & 1][m * 33 + kl * 4 + quad];
              short8 bh1 = HSH[ph & 1][(16 + m) * 33 + kl * 4 + quad];
              short8 bl1 = HSL[ph & 1][(16 + m) * 33 + kl * 4 + quad];
              acc0 = MFMA(wbh[widx], bh0, acc0);
              acc0 = MFMA(wbh[widx], bl0, acc0);
              acc0 = MFMA(wbl[widx], bh0, acc0);
              acc1 = MFMA(wbh[widx], bh1, acc1);
              acc1 = MFMA(wbh[widx], bl1, acc1);
              acc1 = MFMA(wbl[widx], bh1, acc1);
            }
          }
        }
        #pragma unroll
        for (int r = 0; r < 4; ++r) {
          const int rg = hf * 2 + kq;
          gx[(rg * 32 + mt * 16 + quad * 4 + r) * 32 + m]      = acc0[r];
          gx[(rg * 32 + mt * 16 + quad * 4 + r) * 32 + 16 + m] = acc1[r];
        }
        lds_barrier();
        if (tid < 256) {
          const int u = tid >> 5, b = tid & 31;
          float gt[4];
          #pragma unroll
          for (int g2 = 0; g2 < 4; ++g2) {
            const int row = g2 * 8 + u;
            gt[g2] = gx[(row) * 32 + b] + gx[(32 + row) * 32 + b] +
                     gx[(64 + row) * 32 + b] + gx[(96 + row) * 32 + b];
          }
          float gt0 = gt[0] + bB0, gt1 = gt[1] + bB1;
          float gt2 = gt[2] + bB2, gt3 = gt[3] + bB3;
          float cc = sigmoidf_(gt1) * c1r + sigmoidf_(gt0) * tanhf(gt2);
          float hh = sigmoidf_(gt3) * tanhf(cc);
          c1r = cc;
          unsigned h_, l_;
          bf16split(hh, h_, l_);
          const int wpar = s & 1;
          const int j2 = (blk - B0) * 8 + u;
          coh_store_u16(h1h + wpar * 32768 + b * 1024 + j2, h_);
          coh_store_u16(h1l + wpar * 32768 + b * 1024 + j2, l_);
        }
      }
      if (t < kS + 1) flag_barrier(arrive, gen, blk, tid, t);
    }
  } else {
    // ================= C: vocab projection, s = t-2 ====================
    const int growC = (blk - C0) * 16 + m;
    const float byr = byv[(blk - C0) * 16 + (tid & 15)];
    // persistent slice: 4 kk (kl == w) x hi/lo = 32 VGPR
    const short8* ch_ = wyh + quad * 256 + growC;
    const short8* cl_ = wyl + quad * 256 + growC;
    short8 wch[4], wcl[4];
    #pragma unroll
    for (int i = 0; i < 4; ++i) {
      WLOAD(wch[i], &ch_[(i * 8 + w) * 1024]);
      WLOAD(wcl[i], &cl_[(i * 8 + w) * 1024]);
    }
    VM_WAIT(0);

    #pragma unroll 1
    for (int t = 0; t < kS + 2; ++t) {
      const int s = t - 2;
      if (s >= 0 && s < kS) {
        const int rpar = s & 1;
        const unsigned short* gH = h1h + rpar * 32768;
        const unsigned short* gL = h1l + rpar * 32768;
        const unsigned short* pH0 = gH + b0_ * 1024 + kg8;
        const unsigned short* pH1 = pH0 + 16 * 1024;
        const unsigned short* pL0 = gL + b0_ * 1024 + kg8;
        const unsigned short* pL1 = pL0 + 16 * 1024;
        float4 st[2][4];
        stage_issue4(pH0, pH1, pL0, pL1, 0, st[0][0], st[0][1], st[0][2], st[0][3]);
        f32x4 acc0 = {0.f, 0.f, 0.f, 0.f}, acc1 = {0.f, 0.f, 0.f, 0.f};
        #pragma unroll
        for (int ph = 0; ph < 4; ++ph) {
          if (ph < 3)
            stage_issue4(pH0, pH1, pL0, pL1, (ph + 1) * 256,
                         st[(ph + 1) & 1][0], st[(ph + 1) & 1][1],
                         st[(ph + 1) & 1][2], st[(ph + 1) & 1][3]);
          if (ph < 3) { VM_WAIT(4); } else { VM_WAIT(0); }
          stage_write4(&HSH[ph & 1][0], &HSL[ph & 1][0], b0_, kg,
                       st[ph & 1][0], st[ph & 1][1], st[ph & 1][2], st[ph & 1][3]);
          lds_barrier();
          {
            const int kl = w;                  // wave-uniform
            short8 bh0 = HSH[ph & 1][m * 33 + kl * 4 + quad];
            short8 bl0 = HSL[ph & 1][m * 33 + kl * 4 + quad];
            short8 bh1 = HSH[ph & 1][(16 + m) * 33 + kl * 4 + quad];
            short8 bl1 = HSL[ph & 1][(16 + m) * 33 + kl * 4 + quad];
            acc0 = MFMA(wch[ph], bh0, acc0);
            acc0 = MFMA(wch[ph], bl0, acc0);
            acc0 = MFMA(wcl[ph], bh0, acc0);
            acc1 = MFMA(wch[ph], bh1, acc1);
            acc1 = MFMA(wch[ph], bl1, acc1);
            acc1 = MFMA(wcl[ph], bh1, acc1);
          }
        }
        #pragma unroll
        for (int r = 0; r < 4; ++r) {
          gx[(w * 16 + quad * 4 + r) * 32 + m]      = acc0[r];
          gx[(w * 16 + quad * 4 + r) * 32 + 16 + m] = acc1[r];
        }
        lds_barrier();
        {
          const int b = tid >> 4, vl = tid & 15;
          const int vg = (blk - C0) * 16 + vl;
          float sum = byr;
          #pragma unroll
          for (int rg = 0; rg < 8; ++rg) sum += gx[(rg * 16 + vl) * 32 + b];
          out[(s * kB + b) * kV + vg] = sum;
        }
      }
      if (t < kS + 1) flag_barrier(arrive, gen, blk, tid, t);
    }
  }
}

// -------------------------- host launcher ----------------------------------

extern "C" void kernel_launch(void* const* d_in, const int* in_sizes, int n_in,
                              void* d_out, int out_size, void* d_ws, size_t ws_size,
                              hipStream_t stream) {
  const int*   x   = (const int*)d_in[0];
  const float* Wx0 = (const float*)d_in[1];
  const float* Wh0 = (const float*)d_in[2];
  const float* b0v = (const float*)d_in[3];
  const float* Wx1 = (const float*)d_in[4];
  const float* Wh1 = (const float*)d_in[5];
  const float* b1v = (const float*)d_in[6];
  const float* Why = (const float*)d_in[7];
  const float* byv = (const float*)d_in[8];
  unsigned short* wss = (unsigned short*)d_ws;
  float* outp = (float*)d_out;

  hipLaunchKernelGGL(pack_w, dim3(2048), dim3(256), 0, stream,
                     Wh0, wss + WP0H, wss + WP0L, G4H);
  hipLaunchKernelGGL(pack_w, dim3(2048), dim3(256), 0, stream,
                     Wx1, wss + WP1XH, wss + WP1XL, G4H);
  hipLaunchKernelGGL(pack_w, dim3(2048), dim3(256), 0, stream,
                     Wh1, wss + WP1HH, wss + WP1HL, G4H);
  hipLaunchKernelGGL(pack_w, dim3(128), dim3(256), 0, stream,
                     Why, wss + WYH, wss + WYL, kV);
  // zero h arrays (262144 shorts = 131072 u32) + flags/gen (4097 u32)
  hipLaunchKernelGGL(zero_state, dim3(529), dim3(256), 0, stream,
                     (unsigned*)(wss + HOFF), 131072 + 4100);

  hipLaunchKernelGGL(lstm_persist, dim3(NBLK), dim3(NT), 0, stream,
                     x, Wx0, b0v, b1v, byv, wss, outp);
}

// Round 11
// 4362.703 us; speedup vs baseline: 2.3073x; 2.3073x over previous
//
#include <hip/hip_runtime.h>
#include <math.h>

// ---------------------------------------------------------------------------
// Persistent 2-layer LSTM via MFMA split-bf16 (hi+lo, 3-term) fp32 emulation.
// 208 blocks x 512 thr (1/CU). Pipeline: A(64)=layer0 s=t | B(128)=layer1
// s=t-1 | C(16)=proj s=t-2.
// R13: persistent-register weights (zero in-loop weight loads; FETCH -25x).
// R17: WRITE-ONCE h RINGS + plain (L2-cacheable) staging loads. Diagnosis:
// every round pinned at ~5 TB/s of sc0/sc1 LLC-bypass staging (43 MB/step,
// 208 blocks x full h re-read). h arrays are now rings of depth 513 (slot
// s+1 = h[s], slot 0 = zeros): every address written ONCE per kernel, so no
// L1/L2 can hold a stale copy of a line it has never seen -> plain loads are
// correct with NO fence (R16's per-step buffer_inv fence cost ~11 us/step).
// Producers keep sc0/sc1 write-through stores (LLC-visible before flags).
// ~26 blocks/XCD now share one LLC fetch via L2 (34.5 TB/s aggregate).
// Schedule, vmcnt literals, root barrier = R13 verbatim. ws ~186 MB.
// ---------------------------------------------------------------------------

typedef __attribute__((ext_vector_type(8))) short short8;
typedef __attribute__((ext_vector_type(4))) float f32x4;

constexpr int kV = 256, kH = 1024, kB = 32, kS = 512, G4H = 4096;
constexpr int NT = 512, NBLK = 208;
constexpr int NA = 64, B0 = 64, C0 = 192, ROOT = NBLK - 1;

// ws layout in SHORT units
constexpr long SZW = 4194304L;            // shorts per packed 1024x4096 matrix
constexpr long SZY = 262144L;             // shorts per packed Why array
constexpr long WP0H = 0,        WP0L = SZW;
constexpr long WP1XH = 2*SZW,   WP1XL = 3*SZW;
constexpr long WP1HH = 4*SZW,   WP1HL = 5*SZW;
constexpr long WYH  = 6*SZW,    WYL  = 6*SZW + SZY;
constexpr long HOFF = 6*SZW + 2*SZY;      // ring bases
constexpr long RSLOT = 32768L;            // shorts per ring slot [32][1024]
constexpr long RING  = 513L;              // slots (write-once: s+1, slot0=0s)
constexpr long H0H = HOFF;
constexpr long H0L = HOFF + RING * RSLOT;
constexpr long H1H = HOFF + 2 * RING * RSLOT;
constexpr long H1L = HOFF + 3 * RING * RSLOT;
constexpr long FLG = HOFF + 4 * RING * RSLOT;   // flags (u32 view)

#define MFMA(a,b,c) __builtin_amdgcn_mfma_f32_16x16x32_bf16(a, b, c, 0, 0, 0)

#define VM_WAIT(n) do { \
    asm volatile("s_waitcnt vmcnt(" #n ")" ::: "memory"); \
    __builtin_amdgcn_sched_barrier(0); \
  } while (0)

// asm weight load (prevents compiler rematerialization from memory)
#define WLOAD(dst, p) \
  asm volatile("global_load_dwordx4 %0, %1, off" : "=v"(dst) : "v"(p) : "memory")

__device__ __forceinline__ float sigmoidf_(float v) { return 1.f / (1.f + expf(-v)); }

__device__ __forceinline__ void bf16split(float w, unsigned& hi, unsigned& lo) {
  unsigned u = __float_as_uint(w);
  unsigned r = (u + 0x7fffu + ((u >> 16) & 1u)) >> 16;
  float res = w - __uint_as_float(r << 16);
  unsigned u2 = __float_as_uint(res);
  unsigned r2 = (u2 + 0x7fffu + ((u2 >> 16) & 1u)) >> 16;
  hi = r; lo = r2;
}

// ---------------- coherent (cache-bypass) helpers --------------------------

__device__ __forceinline__ void coh_store_u32(unsigned* p, unsigned v) {
  asm volatile("global_store_dword %0, %1, off sc0 sc1" :: "v"(p), "v"(v) : "memory");
}
__device__ __forceinline__ void coh_store_u16(unsigned short* p, unsigned v) {
  asm volatile("global_store_short %0, %1, off sc0 sc1" :: "v"(p), "v"(v) : "memory");
}
__device__ __forceinline__ unsigned coh_load_u32(const unsigned* p) {
  unsigned v;
  asm volatile("global_load_dword %0, %1, off sc0 sc1\n\ts_waitcnt vmcnt(0)"
               : "=v"(v) : "v"(p) : "memory");
  return v;
}

// issue one 256-k quarter of h (hi+lo): 4 PLAIN cacheable 16B loads, NO wait.
// Safe: ring addresses are written exactly once per kernel (no stale lines).
__device__ __forceinline__ void stage_issue4(const unsigned short* pr0h,
                                             const unsigned short* pr1h,
                                             const unsigned short* pr0l,
                                             const unsigned short* pr1l,
                                             int qoff,   // qtr*256 (shorts)
                                             float4& a, float4& b,
                                             float4& c, float4& d) {
  asm volatile(
      "global_load_dwordx4 %0, %4, off\n\t"
      "global_load_dwordx4 %1, %5, off\n\t"
      "global_load_dwordx4 %2, %6, off\n\t"
      "global_load_dwordx4 %3, %7, off"
      : "=&v"(a), "=&v"(b), "=&v"(c), "=&v"(d)
      : "v"(pr0h + qoff), "v"(pr1h + qoff), "v"(pr0l + qoff), "v"(pr1l + qoff)
      : "memory");
}

__device__ __forceinline__ void stage_write4(short8* HH, short8* HL,
                                             int b0_, int kg,
                                             const float4& a, const float4& b,
                                             const float4& c, const float4& d) {
  HH[b0_ * 33 + kg]        = __builtin_bit_cast(short8, a);
  HH[(b0_ + 16) * 33 + kg] = __builtin_bit_cast(short8, b);
  HL[b0_ * 33 + kg]        = __builtin_bit_cast(short8, c);
  HL[(b0_ + 16) * 33 + kg] = __builtin_bit_cast(short8, d);
}

// barrier that does NOT drain vmcnt: LDS-drain + raw s_barrier.
__device__ __forceinline__ void lds_barrier() {
  asm volatile("s_waitcnt lgkmcnt(0)" ::: "memory");
  __builtin_amdgcn_sched_barrier(0);
  __builtin_amdgcn_s_barrier();
  __builtin_amdgcn_sched_barrier(0);
}

// ---------------- two-hop root flag barrier (R13) --------------------------

__device__ __forceinline__ void flag_barrier(unsigned* arrive, unsigned* gen,
                                             int blk, int tid, int t) {
  __syncthreads();                         // drains vmcnt per wave
  const unsigned target = (unsigned)(t + 1);
  if (tid == 0) coh_store_u32(arrive + blk * 16, target);
  if (blk == ROOT) {
    if (tid < 64) {
      const unsigned* q0 = arrive + tid * 16;
      const unsigned* q1 = arrive + (64 + tid) * 16;
      const unsigned* q2 = arrive + (128 + tid) * 16;
      const int i3 = (192 + tid < NBLK) ? (192 + tid) : 0;
      const unsigned* q3 = arrive + i3 * 16;
      int guard = 0;
      for (;;) {
        unsigned a, b, c, d;
        asm volatile(
            "global_load_dword %0, %4, off sc0 sc1\n\t"
            "global_load_dword %1, %5, off sc0 sc1\n\t"
            "global_load_dword %2, %6, off sc0 sc1\n\t"
            "global_load_dword %3, %7, off sc0 sc1\n\t"
            "s_waitcnt vmcnt(0)"
            : "=&v"(a), "=&v"(b), "=&v"(c), "=&v"(d)
            : "v"(q0), "v"(q1), "v"(q2), "v"(q3) : "memory");
        bool ok = (a >= target) && (b >= target) && (c >= target) && (d >= target);
        if (__all(ok)) break;
        if (++guard > (1 << 17)) break;    // anti-hang valve
      }
      if (tid == 0) coh_store_u32(gen, target);
    }
  } else {
    if (tid == 0) {
      int guard = 0;
      while (coh_load_u32(gen) < target) {
        __builtin_amdgcn_s_sleep(1);
        if (++guard > (1 << 17)) break;    // anti-hang valve
      }
    }
  }
  __syncthreads();
}

// -------------------------- prep kernels -----------------------------------

__global__ void pack_w(const float* __restrict__ in, unsigned short* __restrict__ hi,
                       unsigned short* __restrict__ lo, int ncols) {
  int id = blockIdx.x * 256 + threadIdx.x;
  int slab = id / ncols, row = id % ncols;   // slab < 128
  int k0 = (slab >> 2) * 32 + (slab & 3) * 8;
  long ob = ((long)slab * ncols + row) * 8;
  #pragma unroll
  for (int e = 0; e < 8; ++e) {
    float w = in[(long)(k0 + e) * ncols + row];
    unsigned h_, l_;
    bf16split(w, h_, l_);
    hi[ob + e] = (unsigned short)h_;
    lo[ob + e] = (unsigned short)l_;
  }
}

// zero slot 0 of the 4 rings (65536 u32) + flags (4100 u32), write-through
__global__ void zero_init(unsigned short* __restrict__ wss) {
  long i = (long)blockIdx.x * 256 + threadIdx.x;
  if (i < 65536) {
    int arr = (int)(i >> 14), off = (int)(i & 16383);
    unsigned* p = (unsigned*)(wss + HOFF + (long)arr * (RING * RSLOT));
    coh_store_u32(p + off, 0u);
  } else if (i < 65536 + 4100) {
    unsigned* f = (unsigned*)(wss + FLG);
    coh_store_u32(f + (int)(i - 65536), 0u);
  }
}

// -------------------------- main persistent kernel -------------------------

extern "C" __global__ void __launch_bounds__(512, 1)
lstm_persist(const int* __restrict__ x,
             const float* __restrict__ Wx0,
             const float* __restrict__ b0v,
             const float* __restrict__ b1v,
             const float* __restrict__ byv,
             unsigned short* __restrict__ wss,
             float* __restrict__ out) {
  const short8* wp0h  = (const short8*)(wss + WP0H);
  const short8* wp0l  = (const short8*)(wss + WP0L);
  const short8* wp1xh = (const short8*)(wss + WP1XH);
  const short8* wp1xl = (const short8*)(wss + WP1XL);
  const short8* wp1hh = (const short8*)(wss + WP1HH);
  const short8* wp1hl = (const short8*)(wss + WP1HL);
  const short8* wyh   = (const short8*)(wss + WYH);
  const short8* wyl   = (const short8*)(wss + WYL);
  unsigned short* h0h = wss + H0H;             // ring [513][32][1024]
  unsigned short* h0l = wss + H0L;
  unsigned short* h1h = wss + H1H;
  unsigned short* h1l = wss + H1L;
  unsigned* arrive = (unsigned*)(wss + FLG);   // stride-16 flags
  unsigned* gen = arrive + 4096;

  const int tid = threadIdx.x, blk = blockIdx.x;
  const int lane = tid & 63, m = lane & 15, quad = lane >> 4, w = tid >> 6;
  const int b0_ = tid >> 5, kg = tid & 31;     // staging row / chunk
  const int kg8 = kg * 8;

  __shared__ short8 HSH[2][32 * 33];   // 2 x 16.5 KB  h hi quarter (dbuf)
  __shared__ short8 HSL[2][32 * 33];   // 2 x 16.5 KB  h lo quarter (dbuf)
  __shared__ float gx[4096];           // 16 KB partial-sum exchange

  if (blk < NA) {
    // ================= A: layer0 cell, s = t ===========================
    const int g = w >> 1, kh = w & 1, j0A = blk * 16;
    const int ue = tid >> 5, be = tid & 31, j2e = j0A + ue;
    const float bA0 = b0v[j2e],          bA1 = b0v[kH + j2e];
    const float bA2 = b0v[2 * kH + j2e], bA3 = b0v[3 * kH + j2e];
    // persistent weight slice: 16 kk (parity kh) x hi/lo = 128 VGPR
    const short8* ah_ = wp0h + quad * 4096 + (g * 1024 + j0A + m);
    const short8* al_ = wp0l + quad * 4096 + (g * 1024 + j0A + m);
    short8 wah[16], wal[16];
    #pragma unroll
    for (int i = 0; i < 16; ++i) {
      WLOAD(wah[i], &ah_[(2 * i + kh) * 16384]);
      WLOAD(wal[i], &al_[(2 * i + kh) * 16384]);
    }
    VM_WAIT(0);
    float c0r = 0.f;

    #pragma unroll 1
    for (int t = 0; t < kS + 2; ++t) {
      const int s = t;
      if (s < kS) {
        // reads h0[s-1] = ring slot s; writes h0[s] = slot s+1
        const unsigned short* pH0 = h0h + (long)s * RSLOT + b0_ * 1024 + kg8;
        const unsigned short* pH1 = pH0 + 16 * 1024;
        const unsigned short* pL0 = h0l + (long)s * RSLOT + b0_ * 1024 + kg8;
        const unsigned short* pL1 = pL0 + 16 * 1024;
        // xs first (compiler load + its own drain), then asm gather, stages
        const int xs = x[be * kS + s];
        const float* wxp = Wx0 + (long)xs * G4H + j2e;
        float wxi, wxf, wxg, wxo;
        asm volatile(
            "global_load_dword %0, %4, off\n\t"
            "global_load_dword %1, %5, off\n\t"
            "global_load_dword %2, %6, off\n\t"
            "global_load_dword %3, %7, off"
            : "=&v"(wxi), "=&v"(wxf), "=&v"(wxg), "=&v"(wxo)
            : "v"(wxp), "v"(wxp + kH), "v"(wxp + 2 * kH), "v"(wxp + 3 * kH)
            : "memory");
        float4 st[2][4];
        stage_issue4(pH0, pH1, pL0, pL1, 0, st[0][0], st[0][1], st[0][2], st[0][3]);
        f32x4 acc0 = {0.f, 0.f, 0.f, 0.f}, acc1 = {0.f, 0.f, 0.f, 0.f};
        #pragma unroll
        for (int ph = 0; ph < 4; ++ph) {
          if (ph < 3)
            stage_issue4(pH0, pH1, pL0, pL1, (ph + 1) * 256,
                         st[(ph + 1) & 1][0], st[(ph + 1) & 1][1],
                         st[(ph + 1) & 1][2], st[(ph + 1) & 1][3]);
          if (ph < 3) { VM_WAIT(4); } else { VM_WAIT(0); }
          stage_write4(&HSH[ph & 1][0], &HSL[ph & 1][0], b0_, kg,
                       st[ph & 1][0], st[ph & 1][1], st[ph & 1][2], st[ph & 1][3]);
          lds_barrier();
          #pragma unroll
          for (int i2 = 0; i2 < 4; ++i2) {
            const int kl = 2 * i2 + kh;          // runtime kh, fine
            const int widx = ph * 4 + i2;        // compile-time
            short8 bh0 = HSH[ph & 1][m * 33 + kl * 4 + quad];
            short8 bl0 = HSL[ph & 1][m * 33 + kl * 4 + quad];
            short8 bh1 = HSH[ph & 1][(16 + m) * 33 + kl * 4 + quad];
            short8 bl1 = HSL[ph & 1][(16 + m) * 33 + kl * 4 + quad];
            acc0 = MFMA(wah[widx], bh0, acc0);
            acc0 = MFMA(wah[widx], bl0, acc0);
            acc0 = MFMA(wal[widx], bh0, acc0);
            acc1 = MFMA(wah[widx], bh1, acc1);
            acc1 = MFMA(wah[widx], bl1, acc1);
            acc1 = MFMA(wal[widx], bh1, acc1);
          }
        }
        #pragma unroll
        for (int r = 0; r < 4; ++r) {
          gx[(kh * 64 + g * 16 + quad * 4 + r) * 32 + m]      = acc0[r];
          gx[(kh * 64 + g * 16 + quad * 4 + r) * 32 + 16 + m] = acc1[r];
        }
        lds_barrier();
        {
          float gi = gx[(0 + ue) * 32 + be]  + gx[(64 + 0 + ue) * 32 + be]  + wxi + bA0;
          float gf = gx[(16 + ue) * 32 + be] + gx[(64 + 16 + ue) * 32 + be] + wxf + bA1;
          float gg = gx[(32 + ue) * 32 + be] + gx[(64 + 32 + ue) * 32 + be] + wxg + bA2;
          float go = gx[(48 + ue) * 32 + be] + gx[(64 + 48 + ue) * 32 + be] + wxo + bA3;
          float cc = sigmoidf_(gf) * c0r + sigmoidf_(gi) * tanhf(gg);
          float hh = sigmoidf_(go) * tanhf(cc);
          c0r = cc;
          unsigned h_, l_;
          bf16split(hh, h_, l_);
          coh_store_u16(h0h + (long)(s + 1) * RSLOT + be * 1024 + j2e, h_);
          coh_store_u16(h0l + (long)(s + 1) * RSLOT + be * 1024 + j2e, l_);
        }
      }
      if (t < kS + 1) flag_barrier(arrive, gen, blk, tid, t);
    }
  } else if (blk < C0) {
    // ================= B: layer1 cell, s = t-1 =========================
    const int hf = w >> 2, mt = (w >> 1) & 1, kq = w & 1;
    const int rowB = mt * 16 + m;
    const int growB = (rowB >> 3) * 1024 + (blk - B0) * 8 + (rowB & 7);
    const int ub = tid >> 5;
    const int j2b = (blk - B0) * 8 + (ub & 7);
    const float bB0 = b1v[j2b],          bB1 = b1v[kH + j2b];
    const float bB2 = b1v[2 * kH + j2b], bB3 = b1v[3 * kH + j2b];
    // persistent slice: matrix hf, 16 kk (parity kq) x hi/lo = 128 VGPR
    const short8* bh_ = (hf ? wp1hh : wp1xh) + quad * 4096 + growB;
    const short8* bl_ = (hf ? wp1hl : wp1xl) + quad * 4096 + growB;
    short8 wbh[16], wbl[16];
    #pragma unroll
    for (int i = 0; i < 16; ++i) {
      WLOAD(wbh[i], &bh_[(2 * i + kq) * 16384]);
      WLOAD(wbl[i], &bl_[(2 * i + kq) * 16384]);
    }
    VM_WAIT(0);
    float c1r = 0.f;

    #pragma unroll 1
    for (int t = 0; t < kS + 2; ++t) {
      const int s = t - 1;
      if (s >= 0 && s < kS) {
        // reads h0[s] = slot s+1, h1[s-1] = slot s; writes h1[s] = slot s+1
        const unsigned short* pA0h = h0h + (long)(s + 1) * RSLOT + b0_ * 1024 + kg8;
        const unsigned short* pA1h = pA0h + 16 * 1024;
        const unsigned short* pA0l = h0l + (long)(s + 1) * RSLOT + b0_ * 1024 + kg8;
        const unsigned short* pA1l = pA0l + 16 * 1024;
        const unsigned short* pB0h = h1h + (long)s * RSLOT + b0_ * 1024 + kg8;
        const unsigned short* pB1h = pB0h + 16 * 1024;
        const unsigned short* pB0l = h1l + (long)s * RSLOT + b0_ * 1024 + kg8;
        const unsigned short* pB1l = pB0l + 16 * 1024;
        float4 st[2][4];
        stage_issue4(pA0h, pA1h, pA0l, pA1l, 0,
                     st[0][0], st[0][1], st[0][2], st[0][3]);
        f32x4 acc0 = {0.f, 0.f, 0.f, 0.f}, acc1 = {0.f, 0.f, 0.f, 0.f};
        #pragma unroll
        for (int ph = 0; ph < 8; ++ph) {
          const int half = ph >> 2, qtr = ph & 3;
          if (ph < 7) {
            const int p1 = ph + 1, q1 = p1 & 3;
            if ((p1 >> 2) == 0)
              stage_issue4(pA0h, pA1h, pA0l, pA1l, q1 * 256,
                           st[p1 & 1][0], st[p1 & 1][1], st[p1 & 1][2], st[p1 & 1][3]);
            else
              stage_issue4(pB0h, pB1h, pB0l, pB1l, q1 * 256,
                           st[p1 & 1][0], st[p1 & 1][1], st[p1 & 1][2], st[p1 & 1][3]);
          }
          if (ph < 7) { VM_WAIT(4); } else { VM_WAIT(0); }
          stage_write4(&HSH[ph & 1][0], &HSL[ph & 1][0], b0_, kg,
                       st[ph & 1][0], st[ph & 1][1], st[ph & 1][2], st[ph & 1][3]);
          lds_barrier();
          if (hf == half) {
            #pragma unroll
            for (int i2 = 0; i2 < 4; ++i2) {
              const int kl = 2 * i2 + kq;
              const int widx = qtr * 4 + i2;
              short8 bh0 = HSH[ph & 1][m * 33 + kl * 4 + quad];
              short8 bl0 = HSL[ph & 1][m * 33 + kl * 4 + quad];
              short8 bh1 = HSH[ph & 1][(16 + m) * 33 + kl * 4 + quad];
              short8 bl1 = HSL[ph & 1][(16 + m) * 33 + kl * 4 + quad];
              acc0 = MFMA(wbh[widx], bh0, acc0);
              acc0 = MFMA(wbh[widx], bl0, acc0);
              acc0 = MFMA(wbl[widx], bh0, acc0);
              acc1 = MFMA(wbh[widx], bh1, acc1);
              acc1 = MFMA(wbh[widx], bl1, acc1);
              acc1 = MFMA(wbl[widx], bh1, acc1);
            }
          }
        }
        #pragma unroll
        for (int r = 0; r < 4; ++r) {
          const int rg = hf * 2 + kq;
          gx[(rg * 32 + mt * 16 + quad * 4 + r) * 32 + m]      = acc0[r];
          gx[(rg * 32 + mt * 16 + quad * 4 + r) * 32 + 16 + m] = acc1[r];
        }
        lds_barrier();
        if (tid < 256) {
          const int u = tid >> 5, b = tid & 31;
          float gt[4];
          #pragma unroll
          for (int g2 = 0; g2 < 4; ++g2) {
            const int row = g2 * 8 + u;
            gt[g2] = gx[(row) * 32 + b] + gx[(32 + row) * 32 + b] +
                     gx[(64 + row) * 32 + b] + gx[(96 + row) * 32 + b];
          }
          float gt0 = gt[0] + bB0, gt1 = gt[1] + bB1;
          float gt2 = gt[2] + bB2, gt3 = gt[3] + bB3;
          float cc = sigmoidf_(gt1) * c1r + sigmoidf_(gt0) * tanhf(gt2);
          float hh = sigmoidf_(gt3) * tanhf(cc);
          c1r = cc;
          unsigned h_, l_;
          bf16split(hh, h_, l_);
          const int j2 = (blk - B0) * 8 + u;
          coh_store_u16(h1h + (long)(s + 1) * RSLOT + b * 1024 + j2, h_);
          coh_store_u16(h1l + (long)(s + 1) * RSLOT + b * 1024 + j2, l_);
        }
      }
      if (t < kS + 1) flag_barrier(arrive, gen, blk, tid, t);
    }
  } else {
    // ================= C: vocab projection, s = t-2 ====================
    const int growC = (blk - C0) * 16 + m;
    const float byr = byv[(blk - C0) * 16 + (tid & 15)];
    // persistent slice: 4 kk (kl == w) x hi/lo = 32 VGPR
    const short8* ch_ = wyh + quad * 256 + growC;
    const short8* cl_ = wyl + quad * 256 + growC;
    short8 wch[4], wcl[4];
    #pragma unroll
    for (int i = 0; i < 4; ++i) {
      WLOAD(wch[i], &ch_[(i * 8 + w) * 1024]);
      WLOAD(wcl[i], &cl_[(i * 8 + w) * 1024]);
    }
    VM_WAIT(0);

    #pragma unroll 1
    for (int t = 0; t < kS + 2; ++t) {
      const int s = t - 2;
      if (s >= 0 && s < kS) {
        // reads h1[s] = ring slot s+1
        const unsigned short* pH0 = h1h + (long)(s + 1) * RSLOT + b0_ * 1024 + kg8;
        const unsigned short* pH1 = pH0 + 16 * 1024;
        const unsigned short* pL0 = h1l + (long)(s + 1) * RSLOT + b0_ * 1024 + kg8;
        const unsigned short* pL1 = pL0 + 16 * 1024;
        float4 st[2][4];
        stage_issue4(pH0, pH1, pL0, pL1, 0, st[0][0], st[0][1], st[0][2], st[0][3]);
        f32x4 acc0 = {0.f, 0.f, 0.f, 0.f}, acc1 = {0.f, 0.f, 0.f, 0.f};
        #pragma unroll
        for (int ph = 0; ph < 4; ++ph) {
          if (ph < 3)
            stage_issue4(pH0, pH1, pL0, pL1, (ph + 1) * 256,
                         st[(ph + 1) & 1][0], st[(ph + 1) & 1][1],
                         st[(ph + 1) & 1][2], st[(ph + 1) & 1][3]);
          if (ph < 3) { VM_WAIT(4); } else { VM_WAIT(0); }
          stage_write4(&HSH[ph & 1][0], &HSL[ph & 1][0], b0_, kg,
                       st[ph & 1][0], st[ph & 1][1], st[ph & 1][2], st[ph & 1][3]);
          lds_barrier();
          {
            const int kl = w;                  // wave-uniform
            short8 bh0 = HSH[ph & 1][m * 33 + kl * 4 + quad];
            short8 bl0 = HSL[ph & 1][m * 33 + kl * 4 + quad];
            short8 bh1 = HSH[ph & 1][(16 + m) * 33 + kl * 4 + quad];
            short8 bl1 = HSL[ph & 1][(16 + m) * 33 + kl * 4 + quad];
            acc0 = MFMA(wch[ph], bh0, acc0);
            acc0 = MFMA(wch[ph], bl0, acc0);
            acc0 = MFMA(wcl[ph], bh0, acc0);
            acc1 = MFMA(wch[ph], bh1, acc1);
            acc1 = MFMA(wch[ph], bl1, acc1);
            acc1 = MFMA(wcl[ph], bh1, acc1);
          }
        }
        #pragma unroll
        for (int r = 0; r < 4; ++r) {
          gx[(w * 16 + quad * 4 + r) * 32 + m]      = acc0[r];
          gx[(w * 16 + quad * 4 + r) * 32 + 16 + m] = acc1[r];
        }
        lds_barrier();
        {
          const int b = tid >> 4, vl = tid & 15;
          const int vg = (blk - C0) * 16 + vl;
          float sum = byr;
          #pragma unroll
          for (int rg = 0; rg < 8; ++rg) sum += gx[(rg * 16 + vl) * 32 + b];
          out[(s * kB + b) * kV + vg] = sum;
        }
      }
      if (t < kS + 1) flag_barrier(arrive, gen, blk, tid, t);
    }
  }
}

// -------------------------- host launcher ----------------------------------

extern "C" void kernel_launch(void* const* d_in, const int* in_sizes, int n_in,
                              void* d_out, int out_size, void* d_ws, size_t ws_size,
                              hipStream_t stream) {
  const int*   x   = (const int*)d_in[0];
  const float* Wx0 = (const float*)d_in[1];
  const float* Wh0 = (const float*)d_in[2];
  const float* b0v = (const float*)d_in[3];
  const float* Wx1 = (const float*)d_in[4];
  const float* Wh1 = (const float*)d_in[5];
  const float* b1v = (const float*)d_in[6];
  const float* Why = (const float*)d_in[7];
  const float* byv = (const float*)d_in[8];
  unsigned short* wss = (unsigned short*)d_ws;
  float* outp = (float*)d_out;

  hipLaunchKernelGGL(pack_w, dim3(2048), dim3(256), 0, stream,
                     Wh0, wss + WP0H, wss + WP0L, G4H);
  hipLaunchKernelGGL(pack_w, dim3(2048), dim3(256), 0, stream,
                     Wx1, wss + WP1XH, wss + WP1XL, G4H);
  hipLaunchKernelGGL(pack_w, dim3(2048), dim3(256), 0, stream,
                     Wh1, wss + WP1HH, wss + WP1HL, G4H);
  hipLaunchKernelGGL(pack_w, dim3(128), dim3(256), 0, stream,
                     Why, wss + WYH, wss + WYL, kV);
  // zero ring slot 0 (65536 u32) + flags (4100 u32)
  hipLaunchKernelGGL(zero_init, dim3(274), dim3(256), 0, stream, wss);

  hipLaunchKernelGGL(lstm_persist, dim3(NBLK), dim3(NT), 0, stream,
                     x, Wx0, b0v, b1v, byv, wss, outp);
}

// Round 12
// 4205.221 us; speedup vs baseline: 2.3937x; 1.0374x over previous
//
#include <hip/hip_runtime.h>
#include <math.h>

// ---------------------------------------------------------------------------
// Persistent 2-layer LSTM via MFMA split-bf16 (hi+lo, 3-term) fp32 emulation.
// 208 blocks x 512 thr (1/CU). A(64)=layer0 s=t | B(128)=layer1 s=t-1 |
// C(16)=proj s=t-2.
// R13: persistent-register weights (zero in-loop weight loads).
// R17: write-once h rings (depth 513) + plain L2-cacheable staging loads.
// R18: DECOUPLED PER-STAGE BARRIERS + DUAL-GROUP B PHASES.
//  - Dependences: A(t)<-A(t-1); B(t)<-A(t-1),B(t-1); C(t)<-B(t-1). Rings are
//    write-once => no WAR hazards => no global barrier needed. A-group
//    barrier (64 blks, root 63 -> genA); B-group barrier (128 blks, root 191
//    publishes genB when B-flags>=t+1 AND genA>=t+1); C polls genB only.
//    A runs ahead freely; critical path = max(TA,TB), not sum-of-skew.
//  - B phases 8->4: h0-quarter and h1-quarter staged CONCURRENTLY into
//    separate LDS sets (LB[0..3]=h0 dbuf, LB[4..7]=h1 dbuf, 148KB total);
//    wave-group hf=0 does Wx1 x h0, hf=1 does Wh1 x h1 -- every wave MFMAs
//    every phase. vmcnt depth-2 = 8 loads -> VM_WAIT(8).
// ---------------------------------------------------------------------------

typedef __attribute__((ext_vector_type(8))) short short8;
typedef __attribute__((ext_vector_type(4))) float f32x4;

constexpr int kV = 256, kH = 1024, kB = 32, kS = 512, G4H = 4096;
constexpr int NT = 512, NBLK = 208;
constexpr int NA = 64, B0 = 64, C0 = 192;

// ws layout in SHORT units
constexpr long SZW = 4194304L;            // shorts per packed 1024x4096 matrix
constexpr long SZY = 262144L;             // shorts per packed Why array
constexpr long WP0H = 0,        WP0L = SZW;
constexpr long WP1XH = 2*SZW,   WP1XL = 3*SZW;
constexpr long WP1HH = 4*SZW,   WP1HL = 5*SZW;
constexpr long WYH  = 6*SZW,    WYL  = 6*SZW + SZY;
constexpr long HOFF = 6*SZW + 2*SZY;      // ring bases
constexpr long RSLOT = 32768L;            // shorts per ring slot [32][1024]
constexpr long RING  = 513L;              // slots (write-once: s+1, slot0=0s)
constexpr long H0H = HOFF;
constexpr long H0L = HOFF + RING * RSLOT;
constexpr long H1H = HOFF + 2 * RING * RSLOT;
constexpr long H1L = HOFF + 3 * RING * RSLOT;
constexpr long FLG = HOFF + 4 * RING * RSLOT;   // flags (u32 view)

#define MFMA(a,b,c) __builtin_amdgcn_mfma_f32_16x16x32_bf16(a, b, c, 0, 0, 0)

#define VM_WAIT(n) do { \
    asm volatile("s_waitcnt vmcnt(" #n ")" ::: "memory"); \
    __builtin_amdgcn_sched_barrier(0); \
  } while (0)

// asm weight load (prevents compiler rematerialization from memory)
#define WLOAD(dst, p) \
  asm volatile("global_load_dwordx4 %0, %1, off" : "=v"(dst) : "v"(p) : "memory")

__device__ __forceinline__ float sigmoidf_(float v) { return 1.f / (1.f + expf(-v)); }

__device__ __forceinline__ void bf16split(float w, unsigned& hi, unsigned& lo) {
  unsigned u = __float_as_uint(w);
  unsigned r = (u + 0x7fffu + ((u >> 16) & 1u)) >> 16;
  float res = w - __uint_as_float(r << 16);
  unsigned u2 = __float_as_uint(res);
  unsigned r2 = (u2 + 0x7fffu + ((u2 >> 16) & 1u)) >> 16;
  hi = r; lo = r2;
}

// ---------------- coherent (cache-bypass) helpers --------------------------

__device__ __forceinline__ void coh_store_u32(unsigned* p, unsigned v) {
  asm volatile("global_store_dword %0, %1, off sc0 sc1" :: "v"(p), "v"(v) : "memory");
}
__device__ __forceinline__ void coh_store_u16(unsigned short* p, unsigned v) {
  asm volatile("global_store_short %0, %1, off sc0 sc1" :: "v"(p), "v"(v) : "memory");
}
__device__ __forceinline__ unsigned coh_load_u32(const unsigned* p) {
  unsigned v;
  asm volatile("global_load_dword %0, %1, off sc0 sc1\n\ts_waitcnt vmcnt(0)"
               : "=v"(v) : "v"(p) : "memory");
  return v;
}

// issue one 256-k quarter of h (hi+lo): 4 PLAIN cacheable 16B loads, NO wait.
// Safe: ring addresses are written exactly once per kernel (no stale lines).
__device__ __forceinline__ void stage_issue4(const unsigned short* pr0h,
                                             const unsigned short* pr1h,
                                             const unsigned short* pr0l,
                                             const unsigned short* pr1l,
                                             int qoff,   // qtr*256 (shorts)
                                             float4& a, float4& b,
                                             float4& c, float4& d) {
  asm volatile(
      "global_load_dwordx4 %0, %4, off\n\t"
      "global_load_dwordx4 %1, %5, off\n\t"
      "global_load_dwordx4 %2, %6, off\n\t"
      "global_load_dwordx4 %3, %7, off"
      : "=&v"(a), "=&v"(b), "=&v"(c), "=&v"(d)
      : "v"(pr0h + qoff), "v"(pr1h + qoff), "v"(pr0l + qoff), "v"(pr1l + qoff)
      : "memory");
}

__device__ __forceinline__ void stage_write4(short8* HH, short8* HL,
                                             int b0_, int kg,
                                             const float4& a, const float4& b,
                                             const float4& c, const float4& d) {
  HH[b0_ * 33 + kg]        = __builtin_bit_cast(short8, a);
  HH[(b0_ + 16) * 33 + kg] = __builtin_bit_cast(short8, b);
  HL[b0_ * 33 + kg]        = __builtin_bit_cast(short8, c);
  HL[(b0_ + 16) * 33 + kg] = __builtin_bit_cast(short8, d);
}

// barrier that does NOT drain vmcnt: LDS-drain + raw s_barrier.
__device__ __forceinline__ void lds_barrier() {
  asm volatile("s_waitcnt lgkmcnt(0)" ::: "memory");
  __builtin_amdgcn_sched_barrier(0);
  __builtin_amdgcn_s_barrier();
  __builtin_amdgcn_sched_barrier(0);
}

// ---------------- per-stage group barriers ---------------------------------

__device__ __forceinline__ void barrier_A(unsigned* arrive, unsigned* genA,
                                          int blk, int tid, int t) {
  __syncthreads();                         // drains vmcnt per wave
  const unsigned target = (unsigned)(t + 1);
  if (tid == 0) coh_store_u32(arrive + blk * 16, target);
  if (blk == NA - 1) {
    if (tid < 64) {
      const unsigned* q0 = arrive + tid * 16;
      int guard = 0;
      for (;;) {
        unsigned a;
        asm volatile("global_load_dword %0, %1, off sc0 sc1\n\ts_waitcnt vmcnt(0)"
                     : "=&v"(a) : "v"(q0) : "memory");
        if (__all(a >= target)) break;
        if (++guard > (1 << 17)) break;    // anti-hang valve
      }
      if (tid == 0) coh_store_u32(genA, target);
    }
  } else {
    if (tid == 0) {
      int guard = 0;
      while (coh_load_u32(genA) < target) {
        __builtin_amdgcn_s_sleep(1);
        if (++guard > (1 << 17)) break;    // anti-hang valve
      }
    }
  }
  __syncthreads();
}

__device__ __forceinline__ void barrier_B(unsigned* arrive, unsigned* genA,
                                          unsigned* genB, int blk, int tid, int t) {
  __syncthreads();                         // drains vmcnt per wave
  const unsigned target = (unsigned)(t + 1);
  if (tid == 0) coh_store_u32(arrive + blk * 16, target);
  if (blk == C0 - 1) {                     // 191: B root
    if (tid < 64) {
      const unsigned* q1 = arrive + (64 + tid) * 16;
      const unsigned* q2 = arrive + (128 + tid) * 16;
      int guard = 0;
      for (;;) {
        unsigned b, c, ga;
        asm volatile(
            "global_load_dword %0, %3, off sc0 sc1\n\t"
            "global_load_dword %1, %4, off sc0 sc1\n\t"
            "global_load_dword %2, %5, off sc0 sc1\n\t"
            "s_waitcnt vmcnt(0)"
            : "=&v"(b), "=&v"(c), "=&v"(ga)
            : "v"(q1), "v"(q2), "v"(genA) : "memory");
        bool ok = (b >= target) && (c >= target) && (ga >= target);
        if (__all(ok)) break;
        if (++guard > (1 << 17)) break;    // anti-hang valve
      }
      if (tid == 0) coh_store_u32(genB, target);
    }
  } else {
    if (tid == 0) {
      int guard = 0;
      while (coh_load_u32(genB) < target) {
        __builtin_amdgcn_s_sleep(1);
        if (++guard > (1 << 17)) break;    // anti-hang valve
      }
    }
  }
  __syncthreads();
}

__device__ __forceinline__ void barrier_C(unsigned* genB, int tid, int t) {
  __syncthreads();
  const unsigned target = (unsigned)(t + 1);
  if (tid == 0) {
    int guard = 0;
    while (coh_load_u32(genB) < target) {
      __builtin_amdgcn_s_sleep(1);
      if (++guard > (1 << 17)) break;      // anti-hang valve
    }
  }
  __syncthreads();
}

// -------------------------- prep kernels -----------------------------------

__global__ void pack_w(const float* __restrict__ in, unsigned short* __restrict__ hi,
                       unsigned short* __restrict__ lo, int ncols) {
  int id = blockIdx.x * 256 + threadIdx.x;
  int slab = id / ncols, row = id % ncols;   // slab < 128
  int k0 = (slab >> 2) * 32 + (slab & 3) * 8;
  long ob = ((long)slab * ncols + row) * 8;
  #pragma unroll
  for (int e = 0; e < 8; ++e) {
    float w = in[(long)(k0 + e) * ncols + row];
    unsigned h_, l_;
    bf16split(w, h_, l_);
    hi[ob + e] = (unsigned short)h_;
    lo[ob + e] = (unsigned short)l_;
  }
}

// zero slot 0 of the 4 rings (65536 u32) + flags/gens (4160 u32)
__global__ void zero_init(unsigned short* __restrict__ wss) {
  long i = (long)blockIdx.x * 256 + threadIdx.x;
  if (i < 65536) {
    int arr = (int)(i >> 14), off = (int)(i & 16383);
    unsigned* p = (unsigned*)(wss + HOFF + (long)arr * (RING * RSLOT));
    coh_store_u32(p + off, 0u);
  } else if (i < 65536 + 4160) {
    unsigned* f = (unsigned*)(wss + FLG);
    coh_store_u32(f + (int)(i - 65536), 0u);
  }
}

// -------------------------- main persistent kernel -------------------------

extern "C" __global__ void __launch_bounds__(512, 1)
lstm_persist(const int* __restrict__ x,
             const float* __restrict__ Wx0,
             const float* __restrict__ b0v,
             const float* __restrict__ b1v,
             const float* __restrict__ byv,
             unsigned short* __restrict__ wss,
             float* __restrict__ out) {
  const short8* wp0h  = (const short8*)(wss + WP0H);
  const short8* wp0l  = (const short8*)(wss + WP0L);
  const short8* wp1xh = (const short8*)(wss + WP1XH);
  const short8* wp1xl = (const short8*)(wss + WP1XL);
  const short8* wp1hh = (const short8*)(wss + WP1HH);
  const short8* wp1hl = (const short8*)(wss + WP1HL);
  const short8* wyh   = (const short8*)(wss + WYH);
  const short8* wyl   = (const short8*)(wss + WYL);
  unsigned short* h0h = wss + H0H;             // ring [513][32][1024]
  unsigned short* h0l = wss + H0L;
  unsigned short* h1h = wss + H1H;
  unsigned short* h1l = wss + H1L;
  unsigned* arrive = (unsigned*)(wss + FLG);   // stride-16 flags
  unsigned* genA = arrive + 4096;              // separate 64B lines
  unsigned* genB = arrive + 4112;

  const int tid = threadIdx.x, blk = blockIdx.x;
  const int lane = tid & 63, m = lane & 15, quad = lane >> 4, w = tid >> 6;
  const int b0_ = tid >> 5, kg = tid & 31;     // staging row / chunk
  const int kg8 = kg * 8;

  // LB[0..1]: h0/A HSH dbuf; LB[2..3]: h0/A HSL dbuf;
  // LB[4..5]: h1 HSH dbuf;   LB[6..7]: h1 HSL dbuf.   132 KB
  __shared__ short8 LB[8][32 * 33];
  __shared__ float gx[4096];           // 16 KB partial-sum exchange

  if (blk < NA) {
    // ================= A: layer0 cell, s = t ===========================
    const int g = w >> 1, kh = w & 1, j0A = blk * 16;
    const int ue = tid >> 5, be = tid & 31, j2e = j0A + ue;
    const float bA0 = b0v[j2e],          bA1 = b0v[kH + j2e];
    const float bA2 = b0v[2 * kH + j2e], bA3 = b0v[3 * kH + j2e];
    // persistent weight slice: 16 kk (parity kh) x hi/lo = 128 VGPR
    const short8* ah_ = wp0h + quad * 4096 + (g * 1024 + j0A + m);
    const short8* al_ = wp0l + quad * 4096 + (g * 1024 + j0A + m);
    short8 wah[16], wal[16];
    #pragma unroll
    for (int i = 0; i < 16; ++i) {
      WLOAD(wah[i], &ah_[(2 * i + kh) * 16384]);
      WLOAD(wal[i], &al_[(2 * i + kh) * 16384]);
    }
    VM_WAIT(0);
    float c0r = 0.f;

    #pragma unroll 1
    for (int t = 0; t < kS + 2; ++t) {
      const int s = t;
      if (s < kS) {
        // reads h0[s-1] = ring slot s; writes h0[s] = slot s+1
        const unsigned short* pH0 = h0h + (long)s * RSLOT + b0_ * 1024 + kg8;
        const unsigned short* pH1 = pH0 + 16 * 1024;
        const unsigned short* pL0 = h0l + (long)s * RSLOT + b0_ * 1024 + kg8;
        const unsigned short* pL1 = pL0 + 16 * 1024;
        const int xs = x[be * kS + s];
        const float* wxp = Wx0 + (long)xs * G4H + j2e;
        float wxi, wxf, wxg, wxo;
        asm volatile(
            "global_load_dword %0, %4, off\n\t"
            "global_load_dword %1, %5, off\n\t"
            "global_load_dword %2, %6, off\n\t"
            "global_load_dword %3, %7, off"
            : "=&v"(wxi), "=&v"(wxf), "=&v"(wxg), "=&v"(wxo)
            : "v"(wxp), "v"(wxp + kH), "v"(wxp + 2 * kH), "v"(wxp + 3 * kH)
            : "memory");
        float4 st[2][4];
        stage_issue4(pH0, pH1, pL0, pL1, 0, st[0][0], st[0][1], st[0][2], st[0][3]);
        f32x4 acc0 = {0.f, 0.f, 0.f, 0.f}, acc1 = {0.f, 0.f, 0.f, 0.f};
        #pragma unroll
        for (int ph = 0; ph < 4; ++ph) {
          if (ph < 3)
            stage_issue4(pH0, pH1, pL0, pL1, (ph + 1) * 256,
                         st[(ph + 1) & 1][0], st[(ph + 1) & 1][1],
                         st[(ph + 1) & 1][2], st[(ph + 1) & 1][3]);
          if (ph < 3) { VM_WAIT(4); } else { VM_WAIT(0); }
          stage_write4(&LB[ph & 1][0], &LB[2 + (ph & 1)][0], b0_, kg,
                       st[ph & 1][0], st[ph & 1][1], st[ph & 1][2], st[ph & 1][3]);
          lds_barrier();
          #pragma unroll
          for (int i2 = 0; i2 < 4; ++i2) {
            const int kl = 2 * i2 + kh;          // runtime kh, fine
            const int widx = ph * 4 + i2;        // compile-time
            short8 bh0 = LB[ph & 1][m * 33 + kl * 4 + quad];
            short8 bl0 = LB[2 + (ph & 1)][m * 33 + kl * 4 + quad];
            short8 bh1 = LB[ph & 1][(16 + m) * 33 + kl * 4 + quad];
            short8 bl1 = LB[2 + (ph & 1)][(16 + m) * 33 + kl * 4 + quad];
            acc0 = MFMA(wah[widx], bh0, acc0);
            acc0 = MFMA(wah[widx], bl0, acc0);
            acc0 = MFMA(wal[widx], bh0, acc0);
            acc1 = MFMA(wah[widx], bh1, acc1);
            acc1 = MFMA(wah[widx], bl1, acc1);
            acc1 = MFMA(wal[widx], bh1, acc1);
          }
        }
        #pragma unroll
        for (int r = 0; r < 4; ++r) {
          gx[(kh * 64 + g * 16 + quad * 4 + r) * 32 + m]      = acc0[r];
          gx[(kh * 64 + g * 16 + quad * 4 + r) * 32 + 16 + m] = acc1[r];
        }
        lds_barrier();
        {
          float gi = gx[(0 + ue) * 32 + be]  + gx[(64 + 0 + ue) * 32 + be]  + wxi + bA0;
          float gf = gx[(16 + ue) * 32 + be] + gx[(64 + 16 + ue) * 32 + be] + wxf + bA1;
          float gg = gx[(32 + ue) * 32 + be] + gx[(64 + 32 + ue) * 32 + be] + wxg + bA2;
          float go = gx[(48 + ue) * 32 + be] + gx[(64 + 48 + ue) * 32 + be] + wxo + bA3;
          float cc = sigmoidf_(gf) * c0r + sigmoidf_(gi) * tanhf(gg);
          float hh = sigmoidf_(go) * tanhf(cc);
          c0r = cc;
          unsigned h_, l_;
          bf16split(hh, h_, l_);
          coh_store_u16(h0h + (long)(s + 1) * RSLOT + be * 1024 + j2e, h_);
          coh_store_u16(h0l + (long)(s + 1) * RSLOT + be * 1024 + j2e, l_);
        }
      }
      if (t < kS + 1) barrier_A(arrive, genA, blk, tid, t);
    }
  } else if (blk < C0) {
    // ================= B: layer1 cell, s = t-1 =========================
    const int hf = w >> 2, mt = (w >> 1) & 1, kq = w & 1;
    const int rowB = mt * 16 + m;
    const int growB = (rowB >> 3) * 1024 + (blk - B0) * 8 + (rowB & 7);
    const int ub = tid >> 5;
    const int j2b = (blk - B0) * 8 + (ub & 7);
    const float bB0 = b1v[j2b],          bB1 = b1v[kH + j2b];
    const float bB2 = b1v[2 * kH + j2b], bB3 = b1v[3 * kH + j2b];
    // persistent slice: matrix hf, 16 kk (parity kq) x hi/lo = 128 VGPR
    const short8* bh_ = (hf ? wp1hh : wp1xh) + quad * 4096 + growB;
    const short8* bl_ = (hf ? wp1hl : wp1xl) + quad * 4096 + growB;
    short8 wbh[16], wbl[16];
    #pragma unroll
    for (int i = 0; i < 16; ++i) {
      WLOAD(wbh[i], &bh_[(2 * i + kq) * 16384]);
      WLOAD(wbl[i], &bl_[(2 * i + kq) * 16384]);
    }
    VM_WAIT(0);
    float c1r = 0.f;

    #pragma unroll 1
    for (int t = 0; t < kS + 2; ++t) {
      const int s = t - 1;
      if (s >= 0 && s < kS) {
        // reads h0[s] = slot s+1, h1[s-1] = slot s; writes h1[s] = slot s+1
        const unsigned short* pA0h = h0h + (long)(s + 1) * RSLOT + b0_ * 1024 + kg8;
        const unsigned short* pA1h = pA0h + 16 * 1024;
        const unsigned short* pA0l = h0l + (long)(s + 1) * RSLOT + b0_ * 1024 + kg8;
        const unsigned short* pA1l = pA0l + 16 * 1024;
        const unsigned short* pB0h = h1h + (long)s * RSLOT + b0_ * 1024 + kg8;
        const unsigned short* pB1h = pB0h + 16 * 1024;
        const unsigned short* pB0l = h1l + (long)s * RSLOT + b0_ * 1024 + kg8;
        const unsigned short* pB1l = pB0l + 16 * 1024;
        float4 sa[2][4], sb[2][4];
        stage_issue4(pA0h, pA1h, pA0l, pA1l, 0,
                     sa[0][0], sa[0][1], sa[0][2], sa[0][3]);
        stage_issue4(pB0h, pB1h, pB0l, pB1l, 0,
                     sb[0][0], sb[0][1], sb[0][2], sb[0][3]);
        f32x4 acc0 = {0.f, 0.f, 0.f, 0.f}, acc1 = {0.f, 0.f, 0.f, 0.f};
        #pragma unroll
        for (int q = 0; q < 4; ++q) {
          if (q < 3) {
            stage_issue4(pA0h, pA1h, pA0l, pA1l, (q + 1) * 256,
                         sa[(q + 1) & 1][0], sa[(q + 1) & 1][1],
                         sa[(q + 1) & 1][2], sa[(q + 1) & 1][3]);
            stage_issue4(pB0h, pB1h, pB0l, pB1l, (q + 1) * 256,
                         sb[(q + 1) & 1][0], sb[(q + 1) & 1][1],
                         sb[(q + 1) & 1][2], sb[(q + 1) & 1][3]);
          }
          if (q < 3) { VM_WAIT(8); } else { VM_WAIT(0); }
          stage_write4(&LB[q & 1][0], &LB[2 + (q & 1)][0], b0_, kg,
                       sa[q & 1][0], sa[q & 1][1], sa[q & 1][2], sa[q & 1][3]);
          stage_write4(&LB[4 + (q & 1)][0], &LB[6 + (q & 1)][0], b0_, kg,
                       sb[q & 1][0], sb[q & 1][1], sb[q & 1][2], sb[q & 1][3]);
          lds_barrier();
          const short8* GH = &LB[hf * 4 + (q & 1)][0];
          const short8* GL = &LB[hf * 4 + 2 + (q & 1)][0];
          #pragma unroll
          for (int i2 = 0; i2 < 4; ++i2) {
            const int kl = 2 * i2 + kq;
            const int widx = q * 4 + i2;
            short8 bh0 = GH[m * 33 + kl * 4 + quad];
            short8 bl0 = GL[m * 33 + kl * 4 + quad];
            short8 bh1 = GH[(16 + m) * 33 + kl * 4 + quad];
            short8 bl1 = GL[(16 + m) * 33 + kl * 4 + quad];
            acc0 = MFMA(wbh[widx], bh0, acc0);
            acc0 = MFMA(wbh[widx], bl0, acc0);
            acc0 = MFMA(wbl[widx], bh0, acc0);
            acc1 = MFMA(wbh[widx], bh1, acc1);
            acc1 = MFMA(wbh[widx], bl1, acc1);
            acc1 = MFMA(wbl[widx], bh1, acc1);
          }
        }
        #pragma unroll
        for (int r = 0; r < 4; ++r) {
          const int rg = hf * 2 + kq;
          gx[(rg * 32 + mt * 16 + quad * 4 + r) * 32 + m]      = acc0[r];
          gx[(rg * 32 + mt * 16 + quad * 4 + r) * 32 + 16 + m] = acc1[r];
        }
        lds_barrier();
        if (tid < 256) {
          const int u = tid >> 5, b = tid & 31;
          float gt[4];
          #pragma unroll
          for (int g2 = 0; g2 < 4; ++g2) {
            const int row = g2 * 8 + u;
            gt[g2] = gx[(row) * 32 + b] + gx[(32 + row) * 32 + b] +
                     gx[(64 + row) * 32 + b] + gx[(96 + row) * 32 + b];
          }
          float gt0 = gt[0] + bB0, gt1 = gt[1] + bB1;
          float gt2 = gt[2] + bB2, gt3 = gt[3] + bB3;
          float cc = sigmoidf_(gt1) * c1r + sigmoidf_(gt0) * tanhf(gt2);
          float hh = sigmoidf_(gt3) * tanhf(cc);
          c1r = cc;
          unsigned h_, l_;
          bf16split(hh, h_, l_);
          const int j2 = (blk - B0) * 8 + u;
          coh_store_u16(h1h + (long)(s + 1) * RSLOT + b * 1024 + j2, h_);
          coh_store_u16(h1l + (long)(s + 1) * RSLOT + b * 1024 + j2, l_);
        }
      }
      if (t < kS + 1) barrier_B(arrive, genA, genB, blk, tid, t);
    }
  } else {
    // ================= C: vocab projection, s = t-2 ====================
    const int growC = (blk - C0) * 16 + m;
    const float byr = byv[(blk - C0) * 16 + (tid & 15)];
    // persistent slice: 4 kk (kl == w) x hi/lo = 32 VGPR
    const short8* ch_ = wyh + quad * 256 + growC;
    const short8* cl_ = wyl + quad * 256 + growC;
    short8 wch[4], wcl[4];
    #pragma unroll
    for (int i = 0; i < 4; ++i) {
      WLOAD(wch[i], &ch_[(i * 8 + w) * 1024]);
      WLOAD(wcl[i], &cl_[(i * 8 + w) * 1024]);
    }
    VM_WAIT(0);

    #pragma unroll 1
    for (int t = 0; t < kS + 2; ++t) {
      const int s = t - 2;
      if (s >= 0 && s < kS) {
        // reads h1[s] = ring slot s+1
        const unsigned short* pH0 = h1h + (long)(s + 1) * RSLOT + b0_ * 1024 + kg8;
        const unsigned short* pH1 = pH0 + 16 * 1024;
        const unsigned short* pL0 = h1l + (long)(s + 1) * RSLOT + b0_ * 1024 + kg8;
        const unsigned short* pL1 = pL0 + 16 * 1024;
        float4 st[2][4];
        stage_issue4(pH0, pH1, pL0, pL1, 0, st[0][0], st[0][1], st[0][2], st[0][3]);
        f32x4 acc0 = {0.f, 0.f, 0.f, 0.f}, acc1 = {0.f, 0.f, 0.f, 0.f};
        #pragma unroll
        for (int ph = 0; ph < 4; ++ph) {
          if (ph < 3)
            stage_issue4(pH0, pH1, pL0, pL1, (ph + 1) * 256,
                         st[(ph + 1) & 1][0], st[(ph + 1) & 1][1],
                         st[(ph + 1) & 1][2], st[(ph + 1) & 1][3]);
          if (ph < 3) { VM_WAIT(4); } else { VM_WAIT(0); }
          stage_write4(&LB[ph & 1][0], &LB[2 + (ph & 1)][0], b0_, kg,
                       st[ph & 1][0], st[ph & 1][1], st[ph & 1][2], st[ph & 1][3]);
          lds_barrier();
          {
            const int kl = w;                  // wave-uniform
            short8 bh0 = LB[ph & 1][m * 33 + kl * 4 + quad];
            short8 bl0 = LB[2 + (ph & 1)][m * 33 + kl * 4 + quad];
            short8 bh1 = LB[ph & 1][(16 + m) * 33 + kl * 4 + quad];
            short8 bl1 = LB[2 + (ph & 1)][(16 + m) * 33 + kl * 4 + quad];
            acc0 = MFMA(wch[ph], bh0, acc0);
            acc0 = MFMA(wch[ph], bl0, acc0);
            acc0 = MFMA(wcl[ph], bh0, acc0);
            acc1 = MFMA(wch[ph], bh1, acc1);
            acc1 = MFMA(wch[ph], bl1, acc1);
            acc1 = MFMA(wcl[ph], bh1, acc1);
          }
        }
        #pragma unroll
        for (int r = 0; r < 4; ++r) {
          gx[(w * 16 + quad * 4 + r) * 32 + m]      = acc0[r];
          gx[(w * 16 + quad * 4 + r) * 32 + 16 + m] = acc1[r];
        }
        lds_barrier();
        {
          const int b = tid >> 4, vl = tid & 15;
          const int vg = (blk - C0) * 16 + vl;
          float sum = byr;
          #pragma unroll
          for (int rg = 0; rg < 8; ++rg) sum += gx[(rg * 16 + vl) * 32 + b];
          out[(s * kB + b) * kV + vg] = sum;
        }
      }
      if (t < kS + 1) barrier_C(genB, tid, t);
    }
  }
}

// -------------------------- host launcher ----------------------------------

extern "C" void kernel_launch(void* const* d_in, const int* in_sizes, int n_in,
                              void* d_out, int out_size, void* d_ws, size_t ws_size,
                              hipStream_t stream) {
  const int*   x   = (const int*)d_in[0];
  const float* Wx0 = (const float*)d_in[1];
  const float* Wh0 = (const float*)d_in[2];
  const float* b0v = (const float*)d_in[3];
  const float* Wx1 = (const float*)d_in[4];
  const float* Wh1 = (const float*)d_in[5];
  const float* b1v = (const float*)d_in[6];
  const float* Why = (const float*)d_in[7];
  const float* byv = (const float*)d_in[8];
  unsigned short* wss = (unsigned short*)d_ws;
  float* outp = (float*)d_out;

  hipLaunchKernelGGL(pack_w, dim3(2048), dim3(256), 0, stream,
                     Wh0, wss + WP0H, wss + WP0L, G4H);
  hipLaunchKernelGGL(pack_w, dim3(2048), dim3(256), 0, stream,
                     Wx1, wss + WP1XH, wss + WP1XL, G4H);
  hipLaunchKernelGGL(pack_w, dim3(2048), dim3(256), 0, stream,
                     Wh1, wss + WP1HH, wss + WP1HL, G4H);
  hipLaunchKernelGGL(pack_w, dim3(128), dim3(256), 0, stream,
                     Why, wss + WYH, wss + WYL, kV);
  // zero ring slot 0 (65536 u32) + flags/gens (4160 u32)
  hipLaunchKernelGGL(zero_init, dim3(274), dim3(256), 0, stream, wss);

  hipLaunchKernelGGL(lstm_persist, dim3(NBLK), dim3(NT), 0, stream,
                     x, Wx0, b0v, b1v, byv, wss, outp);
}